// Round 6
// baseline (304.328 us; speedup 1.0000x reference)
//
#include <hip/hip_runtime.h>
#include <stdint.h>

#define B_ 8
#define N_ 2048
#define F_ 256

typedef unsigned short u16;
typedef __attribute__((ext_vector_type(8))) short bf16x8;   // 8 bf16 in 4 VGPRs
typedef __attribute__((ext_vector_type(4))) float f32x4;

// round-to-nearest-even f32 -> bf16
__device__ __forceinline__ u16 f2bf(float f) {
    uint32_t u = __builtin_bit_cast(uint32_t, f);
    u += 0x7FFFu + ((u >> 16) & 1u);
    return (u16)(u >> 16);
}
__device__ __forceinline__ uint32_t pack2(float a, float b) {
    return (uint32_t)f2bf(a) | ((uint32_t)f2bf(b) << 16);
}

// async global->LDS, 16B per lane. LDS dest must be wave-uniform base; HW adds lane*16.
__device__ __forceinline__ void gload_lds16(const void* g, void* lds_uniform_base) {
    __builtin_amdgcn_global_load_lds(
        (const __attribute__((address_space(1))) uint32_t*)g,
        (__attribute__((address_space(3))) uint32_t*)lds_uniform_base, 16, 0, 0);
}

// ---------------------------------------------------------------------------
// K1 (k_adj): pure adj stream, 16-row x 1024-col sub-panels.
// Grid (128 panels, 2 col-halves, 8 batches) = 2048 blocks = 8/CU = 100% occ.
//   - adj_bf = bf16(adj)
//   - pcol[b][panel][j]: per-16-row-panel column partials (each elem written once)
//   - prow[half][b][i]: half-width row sums (LN adds the two halves)
// ---------------------------------------------------------------------------
__global__ __launch_bounds__(256) void k_adj(const float* __restrict__ adj,
                                             u16* __restrict__ adj_bf,
                                             float* __restrict__ pcol,
                                             float* __restrict__ prow) {
    const int panel = blockIdx.x, half = blockIdx.y, b = blockIdx.z;
    const int t = threadIdx.x, w = t >> 6, l = t & 63;
    const float* base = adj + ((size_t)b * N_ + (size_t)panel * 16) * N_ + half * 1024;
    u16* abf = adj_bf + ((size_t)b * N_ + (size_t)panel * 16) * N_ + half * 1024;
    float c[4];
#pragma unroll
    for (int e = 0; e < 4; ++e) c[e] = 0.f;
    __shared__ float rs[16][4];
#pragma unroll 4
    for (int r = 0; r < 16; ++r) {
        const float4 v = *(const float4*)(base + (size_t)r * N_ + t * 4);
        c[0] += v.x; c[1] += v.y; c[2] += v.z; c[3] += v.w;
        *(uint2*)&abf[(size_t)r * N_ + t * 4] = make_uint2(pack2(v.x, v.y), pack2(v.z, v.w));
        float s = (v.x + v.y) + (v.z + v.w);
#pragma unroll
        for (int off = 32; off; off >>= 1) s += __shfl_xor(s, off);
        if (l == 0) rs[r][w] = s;
    }
    float4* pc = (float4*)(pcol + ((size_t)(b * 128 + panel)) * N_ + half * 1024);
    pc[t] = make_float4(c[0], c[1], c[2], c[3]);
    __syncthreads();
    if (t < 16)
        prow[(size_t)half * (B_ * N_) + (size_t)b * N_ + panel * 16 + t]
            = rs[t][0] + rs[t][1] + rs[t][2] + rs[t][3];
}

// ---------------------------------------------------------------------------
// K2 (k_mid), role by blockIdx.x:
//   [0,512)   LayerNorm -> xn (row-major) + yT ([b][f][n], s_in folded)
//   [512,576) reduce pcol partials (128 per column) -> deg_col
//   [576,584) weight prep: WcT = (Ws+Wn)^T, WnT = (-Wn)^T, bf16
// ---------------------------------------------------------------------------
__global__ __launch_bounds__(256) void k_mid(const float* __restrict__ x,
                                             const float* __restrict__ gamma,
                                             const float* __restrict__ beta,
                                             const float* __restrict__ prow,
                                             const float* __restrict__ pcol,
                                             const float* __restrict__ Ws,
                                             const float* __restrict__ Wn,
                                             u16* __restrict__ xn,
                                             u16* __restrict__ yT,
                                             float* __restrict__ deg_col,
                                             u16* __restrict__ WcT,
                                             u16* __restrict__ WnT) {
    const int bx = blockIdx.x;
    const int t = threadIdx.x;
    __shared__ u16 yt[256 * 34];                       // [f][jj], pad 34
    if (bx < 512) {                                    // ---- LayerNorm role
        const int b = bx >> 6, panel = bx & 63;
        const int w = t >> 6, l = t & 63;
        float g[4], be[4];
#pragma unroll
        for (int m = 0; m < 4; ++m) { g[m] = gamma[l + 64 * m]; be[m] = beta[l + 64 * m]; }
        for (int rr = 0; rr < 8; ++rr) {
            const int jj = w * 8 + rr;
            const int j = panel * 32 + jj;
            const float rowsum = prow[(size_t)b * N_ + j] + prow[(size_t)(B_ * N_) + (size_t)b * N_ + j];
            const float sin_ = (rowsum != 0.f) ? rsqrtf(rowsum) : 0.f;
            const float* xp = x + ((size_t)b * N_ + j) * F_;
            float v[4], s = 0.f, ss = 0.f;
#pragma unroll
            for (int m = 0; m < 4; ++m) { v[m] = xp[l + 64 * m]; s += v[m]; ss += v[m] * v[m]; }
#pragma unroll
            for (int off = 32; off; off >>= 1) { s += __shfl_xor(s, off); ss += __shfl_xor(ss, off); }
            const float mu = s * (1.f / 256.f);
            const float var = ss * (1.f / 256.f) - mu * mu;
            const float rstd = rsqrtf(var + 1e-5f);
            u16* xnp = xn + ((size_t)b * N_ + j) * F_;
#pragma unroll
            for (int m = 0; m < 4; ++m) {
                const float xv = (v[m] - mu) * rstd * g[m] + be[m];
                xnp[l + 64 * m] = f2bf(xv);
                yt[(l + 64 * m) * 34 + jj] = f2bf(sin_ * xv);
            }
        }
        __syncthreads();
#pragma unroll
        for (int m2 = 0; m2 < 2; ++m2) {
            const int f = (t >> 1) + 128 * m2;
            const int jj0 = (t & 1) * 16;
            uint32_t vals[8];
#pragma unroll
            for (int e = 0; e < 8; ++e) vals[e] = *(const uint32_t*)&yt[f * 34 + jj0 + 2 * e];
            uint4* dst = (uint4*)(yT + ((size_t)b * F_ + f) * N_ + panel * 32 + jj0);
            dst[0] = make_uint4(vals[0], vals[1], vals[2], vals[3]);
            dst[1] = make_uint4(vals[4], vals[5], vals[6], vals[7]);
        }
    } else if (bx < 576) {                             // ---- deg_col reduce role
        const int tid = (bx - 512) * 256 + t;          // 16384 = 8 * 2048
        const int b = tid >> 11, j = tid & 2047;
        const float* p = pcol + (size_t)b * 128 * N_ + j;
        float s = 0.f;
#pragma unroll 8
        for (int g = 0; g < 128; ++g) s += p[(size_t)g * N_];
        deg_col[tid] = s;
    } else {                                           // ---- weight prep role
        const int rel = bx - 576;
#pragma unroll 4
        for (int e = 0; e < 32; ++e) {
            const int idx = rel * 8192 + e * 256 + t;  // idx = k*256 + o
            const int k = idx >> 8, o = idx & 255;
            const float a = Ws[idx], q = Wn[idx];
            WcT[o * 256 + k] = f2bf(a + q);
            WnT[o * 256 + k] = f2bf(-q);
        }
    }
}

// ---------------------------------------------------------------------------
// K3 (k_gemm1): z[b,i,f] = bf16( s_out[b,i] * sum_j adj_bf[b,i,j] * yT[b,f,j] )
// m97 structure: 256 thr / 4 waves, 64x128 tile, BK=32, single-buffered
// 2-barrier loop, A+B both gload_lds. Grid 512 = 2 blocks/CU (cross-block
// overlap fills the barrier drain). b = blk&7: batch pinned to one XCD
// (yT[b] 1MB L2-resident); nt pairs sharing an A-panel dispatch-adjacent.
// ---------------------------------------------------------------------------
__global__ __launch_bounds__(256) void k_gemm1(const u16* __restrict__ adj_bf,
                                               const u16* __restrict__ yT,
                                               const float* __restrict__ deg_col,
                                               u16* __restrict__ z) {
    const int blk = blockIdx.x;               // 512 blocks
    const int b = blk & 7;
    const int kk = blk >> 3;                  // 0..63
    const int nt = kk & 1;
    const int m = kk >> 1;                    // 0..31
    const int i0 = m * 64, f0 = nt * 128;
    const int t = threadIdx.x, w = t >> 6, l = t & 63;
    const int wr = w >> 1, wc = w & 1;        // wave -> 32x64 subtile
    alignas(16) __shared__ u16 As[64 * 32];   // 4 KB
    alignas(16) __shared__ u16 Bs[128 * 32];  // 8 KB
    f32x4 acc[2][4];
#pragma unroll
    for (int mi = 0; mi < 2; ++mi)
#pragma unroll
        for (int ni = 0; ni < 4; ++ni) acc[mi][ni] = (f32x4)0.f;

    const u16* abase = adj_bf + ((size_t)b * N_ + i0) * N_;
    const u16* ybase = yT + ((size_t)b * F_ + f0) * (size_t)N_;
    const int lr = l >> 2, lb = (l & 3) * 16; // lane -> row-in-16, byte-in-row

    for (int kt = 0; kt < 64; ++kt) {
        const int k0b = kt * 64;              // byte offset along k (32 bf16)
        // A: 64x32 bf16 = 4 KB, one issue (wave w covers rows w*16..+16)
        gload_lds16((const char*)(abase + (size_t)(w * 16 + lr) * N_) + k0b + lb,
                    (char*)As + (w << 10));
        // B: 128x32 bf16 = 8 KB, two issues
#pragma unroll
        for (int q = 0; q < 2; ++q)
            gload_lds16((const char*)(ybase + (size_t)(q * 64 + w * 16 + lr) * N_) + k0b + lb,
                        (char*)Bs + q * 4096 + (w << 10));
        __syncthreads();
        bf16x8 af[2], bfr[4];
#pragma unroll
        for (int mi = 0; mi < 2; ++mi)
            af[mi] = *(const bf16x8*)&As[(wr * 32 + mi * 16 + (l & 15)) * 32 + (l >> 4) * 8];
#pragma unroll
        for (int ni = 0; ni < 4; ++ni)
            bfr[ni] = *(const bf16x8*)&Bs[(wc * 64 + ni * 16 + (l & 15)) * 32 + (l >> 4) * 8];
#pragma unroll
        for (int mi = 0; mi < 2; ++mi)
#pragma unroll
            for (int ni = 0; ni < 4; ++ni)
                acc[mi][ni] = __builtin_amdgcn_mfma_f32_16x16x32_bf16(af[mi], bfr[ni], acc[mi][ni], 0, 0, 0);
        __syncthreads();
    }
    // epilogue: z = bf16(s_out * acc). C/D: col=lane&15, row=(lane>>4)*4+reg
#pragma unroll
    for (int mi = 0; mi < 2; ++mi) {
#pragma unroll
        for (int r = 0; r < 4; ++r) {
            const int row = i0 + wr * 32 + mi * 16 + (l >> 4) * 4 + r;
            const float d = deg_col[(size_t)b * N_ + row];
            const float so = (d != 0.f) ? rsqrtf(d) : 0.f;
#pragma unroll
            for (int ni = 0; ni < 4; ++ni) {
                const int col = f0 + wc * 64 + ni * 16 + (l & 15);
                z[((size_t)b * N_ + row) * F_ + col] = f2bf(so * acc[mi][ni][r]);
            }
        }
    }
}

// ---------------------------------------------------------------------------
// K4 (k_gemm2): out = softplus( xn @ (Ws+Wn) + z @ (-Wn) ) — virtual K=512.
// Same 64x128-tile / 256-thr structure; grid 512 = 2 blocks/CU.
// ---------------------------------------------------------------------------
__global__ __launch_bounds__(256) void k_gemm2(const u16* __restrict__ xn,
                                               const u16* __restrict__ z,
                                               const u16* __restrict__ WcT,
                                               const u16* __restrict__ WnT,
                                               float* __restrict__ out) {
    const int blk = blockIdx.x;               // 512 blocks
    const int xcd = blk & 7;
    const int kk = blk >> 3;                  // 0..63
    const int nt = kk & 1;
    const int mt = xcd + 8 * (kk >> 1);       // 0..255 (16384 rows / 64)
    const int r0 = mt * 64, o0 = nt * 128;
    const int t = threadIdx.x, w = t >> 6, l = t & 63;
    const int wr = w >> 1, wc = w & 1;
    alignas(16) __shared__ u16 As[64 * 32];
    alignas(16) __shared__ u16 Bs[128 * 32];
    f32x4 acc[2][4];
#pragma unroll
    for (int mi = 0; mi < 2; ++mi)
#pragma unroll
        for (int ni = 0; ni < 4; ++ni) acc[mi][ni] = (f32x4)0.f;

    const int lr = l >> 2, lb = (l & 3) * 16;

    for (int kt = 0; kt < 16; ++kt) {
        const u16* asrc = (kt < 8) ? xn : z;
        const u16* bsrc = (kt < 8) ? WcT : WnT;
        const int kk0b = (kt & 7) * 64;       // byte offset along k
        gload_lds16((const char*)(asrc + (size_t)(r0 + w * 16 + lr) * F_) + kk0b + lb,
                    (char*)As + (w << 10));
#pragma unroll
        for (int q = 0; q < 2; ++q)
            gload_lds16((const char*)(bsrc + (size_t)(o0 + q * 64 + w * 16 + lr) * F_) + kk0b + lb,
                        (char*)Bs + q * 4096 + (w << 10));
        __syncthreads();
        bf16x8 af[2], bfr[4];
#pragma unroll
        for (int mi = 0; mi < 2; ++mi)
            af[mi] = *(const bf16x8*)&As[(wr * 32 + mi * 16 + (l & 15)) * 32 + (l >> 4) * 8];
#pragma unroll
        for (int ni = 0; ni < 4; ++ni)
            bfr[ni] = *(const bf16x8*)&Bs[(wc * 64 + ni * 16 + (l & 15)) * 32 + (l >> 4) * 8];
#pragma unroll
        for (int mi = 0; mi < 2; ++mi)
#pragma unroll
            for (int ni = 0; ni < 4; ++ni)
                acc[mi][ni] = __builtin_amdgcn_mfma_f32_16x16x32_bf16(af[mi], bfr[ni], acc[mi][ni], 0, 0, 0);
        __syncthreads();
    }
#pragma unroll
    for (int mi = 0; mi < 2; ++mi) {
#pragma unroll
        for (int r = 0; r < 4; ++r) {
            const int rr = r0 + wr * 32 + mi * 16 + (l >> 4) * 4 + r;
#pragma unroll
            for (int ni = 0; ni < 4; ++ni) {
                const int cc = o0 + wc * 64 + ni * 16 + (l & 15);
                const float p = acc[mi][ni][r];
                out[(size_t)rr * F_ + cc] = (p > 20.f) ? p : log1pf(expf(p));
            }
        }
    }
}

// ---------------------------------------------------------------------------
extern "C" void kernel_launch(void* const* d_in, const int* in_sizes, int n_in,
                              void* d_out, int out_size, void* d_ws, size_t ws_size,
                              hipStream_t stream) {
    (void)in_sizes; (void)n_in; (void)out_size; (void)ws_size;
    const float* x     = (const float*)d_in[0];
    const float* adj   = (const float*)d_in[1];
    const float* gamma = (const float*)d_in[2];
    const float* beta  = (const float*)d_in[3];
    const float* Ws    = (const float*)d_in[4];
    const float* Wn    = (const float*)d_in[5];
    float* out = (float*)d_out;

    char* ws = (char*)d_ws;
    float* deg_col = (float*)(ws + 0);                 //  64 KB
    float* prow    = (float*)(ws + 65536);             // 128 KB [2][B][N]
    u16* xn     = (u16*)(ws + 196608);                 // 8.0 MB
    u16* yT     = (u16*)(ws + 8585216);                // 8.0 MB
    u16* z      = (u16*)(ws + 16973824);               // 8.0 MB
    u16* WcT    = (u16*)(ws + 25362432);               // 128 KB
    u16* WnT    = (u16*)(ws + 25493504);               // 128 KB
    u16* adj_bf = (u16*)(ws + 25624576);               // 67.1 MB (total ~92.7 MB)
    // pcol (8 MB: [B][128][N] column partials) aliases the z region: fully
    // consumed by k_mid before k_gemm1 writes z.
    float* pcol = (float*)z;

    k_adj  <<<dim3(128, 2, 8), 256, 0, stream>>>(adj, adj_bf, pcol, prow);
    k_mid  <<<584, 256, 0, stream>>>(x, gamma, beta, prow, pcol, Ws, Wn,
                                     xn, yT, deg_col, WcT, WnT);
    k_gemm1<<<512, 256, 0, stream>>>(adj_bf, yT, deg_col, z);
    k_gemm2<<<512, 256, 0, stream>>>(xn, z, WcT, WnT, out);
}